// Round 3
// baseline (443.069 us; speedup 1.0000x reference)
//
#include <hip/hip_runtime.h>
#include <hip/hip_bf16.h>
#include <cstddef>
#include <cstdint>

#define B_   2
#define LQ_  2048
#define LK_  2048
#define H_   8
#define QB   8       // queries per block
#define KB   32      // keys per chunk
#define NW   4       // waves per block
#define KSPLIT 2
#define KEYS_PER_SPLIT (LK_/KSPLIT)   // 1024
#define NCH (KEYS_PER_SPLIT/KB)       // 32 chunks per block

// ws layout (float slot offsets)
#define OFF_QIT  0
#define OFF_QC   131072
#define OFF_KIT  262144
#define OFF_KC   393216
#define OFF_VB   524288      // ushort[B*LK*256] bf16 V  (524288 float slots)
#define OFF_OUTP 1048576     // ushort[KSPLIT*B*LQ*256] bf16 partial out (1048576 slots)
#define OFF_LP   2097152     // float[KSPLIT*B*LQ*8] partial denominators
// total 2162688 floats = 8.65 MB

__device__ __forceinline__ unsigned short f2bf(float f) {
    unsigned int x = __float_as_uint(f);
    unsigned int r = x + 0x7FFFu + ((x >> 16) & 1u);   // round-to-nearest-even
    return (unsigned short)(r >> 16);
}
__device__ __forceinline__ float bf2f(unsigned short u) {
    return __uint_as_float(((unsigned int)u) << 16);
}

// ---------------------------------------------------------------------------
// Fused small projections: Qit, Qc, Kit, Kc  (all [4096 rows] x 32 cols)
// ---------------------------------------------------------------------------
__global__ __launch_bounds__(256)
void proj_qk_kernel(const float* __restrict__ Aq_it, const float* __restrict__ Aq_c,
                    const float* __restrict__ Ak_it, const float* __restrict__ Ak_c,
                    const float* __restrict__ Wq_it, const float* __restrict__ Wq_c,
                    const float* __restrict__ Wk_it, const float* __restrict__ Wk_c,
                    float* __restrict__ ws)
{
    int idx = blockIdx.x * 256 + threadIdx.x;
    int seg = idx >> 17;
    int off = idx & 131071;
    int r = off >> 5;
    int c = off & 31;
    const float* A; const float* W; int K; float* O;
    if (seg == 0)      { A = Aq_it; W = Wq_it; K = 256; O = ws + OFF_QIT; }
    else if (seg == 1) { A = Aq_c;  W = Wq_c;  K = 128; O = ws + OFF_QC;  }
    else if (seg == 2) { A = Ak_it; W = Wk_it; K = 256; O = ws + OFF_KIT; }
    else               { A = Ak_c;  W = Wk_c;  K = 128; O = ws + OFF_KC;  }
    const float* a = A + (size_t)r * K;
    float s = 0.f;
    #pragma unroll 8
    for (int k = 0; k < K; ++k)
        s = fmaf(a[k], W[k * 32 + c], s);
    O[off] = s;
}

// ---------------------------------------------------------------------------
// V projection: keys_it [4096,256] @ Wv [256,256] -> bf16 V [4096,256]
// Thread per (row, 4-col group). 1024 blocks.
// ---------------------------------------------------------------------------
__global__ __launch_bounds__(256)
void proj_v_kernel(const float* __restrict__ A, const float* __restrict__ Wv,
                   unsigned short* __restrict__ Vb)
{
    int gid = blockIdx.x * 256 + threadIdx.x;      // 0..262143
    int r  = gid >> 6;                             // 0..4095
    int c4 = gid & 63;                             // float4 col group
    const float* a = A + (size_t)r * 256;
    const float4* w4 = (const float4*)Wv;          // [256][64]
    float4 acc = {0.f, 0.f, 0.f, 0.f};
    #pragma unroll 4
    for (int k = 0; k < 256; ++k) {
        float av = a[k];
        float4 wv = w4[(size_t)k * 64 + c4];
        acc.x = fmaf(av, wv.x, acc.x);
        acc.y = fmaf(av, wv.y, acc.y);
        acc.z = fmaf(av, wv.z, acc.z);
        acc.w = fmaf(av, wv.w, acc.w);
    }
    ushort4 o;
    o.x = f2bf(acc.x); o.y = f2bf(acc.y); o.z = f2bf(acc.z); o.w = f2bf(acc.w);
    *(ushort4*)&Vb[(size_t)r * 256 + c4 * 4] = o;
}

// ---------------------------------------------------------------------------
// Fused dual-stream attention, NO max subtraction (scores provably tiny),
// key-split partials. Block: 8 queries, 4 waves; half-wave per query; KB=32.
// ---------------------------------------------------------------------------
__global__ __launch_bounds__(256, 4)
void attn_kernel(const float* __restrict__ ws,
                 const float* __restrict__ sigma,
                 const float* __restrict__ noise,
                 const float* __restrict__ Whdp,
                 const float* __restrict__ bhdp,
                 const int* __restrict__ key_mask,
                 float* __restrict__ ws_out)
{
    const int tid  = threadIdx.x;
    const int w    = tid >> 6;
    const int lane = tid & 63;
    const int half = lane >> 5;
    const int lj   = lane & 31;
    const int b    = blockIdx.y & 1;
    const int kz   = blockIdx.y >> 1;
    const int q0   = blockIdx.x * QB;
    const int qloc = w * 2 + half;                 // 0..7
    const int q    = q0 + qloc;
    const int hl   = lane >> 3;                    // PV head 0..7
    const int d0   = (lane & 7) * 4;               // PV dim group

    __shared__ float Qs[QB][68];                   // pad 68: 8 distinct bank quads
    __shared__ unsigned short Vb[KB][256];         // bf16, 16 KB
    __shared__ float Ps[NW][KB][H_][2];            // 8 KB

    // ---- stage Q tile (8 rows x 64 floats: it | ctx) ----
    if (tid < 128) {
        int r = tid >> 4, t = tid & 15;
        int c = t * 4;
        float4 v;
        if (c < 32)
            v = *(const float4*)&ws[OFF_QIT + ((size_t)b * LQ_ + q0 + r) * 32 + c];
        else
            v = *(const float4*)&ws[OFF_QC + ((size_t)b * LQ_ + q0 + r) * 32 + (c - 32)];
        *(float4*)&Qs[r][c] = v;
    }

    const float s0 = sigma[b * 2 + 0], s1 = sigma[b * 2 + 1];
    const float a0 = s0 * s0, a1 = s1 * s1;
    const float rsd = 0.17677669529663687f;        // 1/sqrt(32)
    float w0s[H_], w1s[H_], bhs[H_];
    #pragma unroll
    for (int h = 0; h < H_; ++h) {
        w0s[h] = Whdp[h]      * rsd;
        w1s[h] = Whdp[H_ + h] * rsd;
        bhs[h] = bhdp[h]      * rsd;
    }

    float l_reg[H_];
    #pragma unroll
    for (int h = 0; h < H_; ++h) l_reg[h] = 0.f;
    float acc0[4] = {0.f,0.f,0.f,0.f}, acc1[4] = {0.f,0.f,0.f,0.f};

    const int kbase = kz * KEYS_PER_SPLIT;
    const float* KitG = ws + OFF_KIT + (size_t)b * LK_ * 32;
    const float* KcG  = ws + OFF_KC  + (size_t)b * LK_ * 32;
    const unsigned short* VbG = (const unsigned short*)(ws + OFF_VB) + (size_t)b * LK_ * 256;
    const float* n0p = noise + ((size_t)(b * 2 + 0) * LQ_ + q) * LK_ + kbase;
    const float* n1p = noise + ((size_t)(b * 2 + 1) * LQ_ + q) * LK_ + kbase;
    const int*   km  = key_mask + b * LK_ + kbase;

    __syncthreads();                               // Qs ready

    for (int ch = 0; ch < NCH; ++ch) {
        const int k0 = ch * KB;

        // ---- stage Vb (16 KB, bf16) ----
        {
            const uint4* src = (const uint4*)(VbG + (size_t)(kbase + k0) * 256);
            uint4* dst = (uint4*)&Vb[0][0];
            #pragma unroll
            for (int i = 0; i < 4; ++i) dst[tid + 256 * i] = src[tid + 256 * i];
        }

        // ---- score phase: lane lj = key, half-wave = query ----
        const int kidx = k0 + lj;
        const bool kmb = km[kidx] != 0;
        const float n0 = n0p[kidx];
        const float n1 = n1p[kidx];

        float4 kr[8];
        {
            const float4* kp = (const float4*)(KitG + (size_t)(kbase + kidx) * 32);
            #pragma unroll
            for (int t = 0; t < 8; ++t) kr[t] = kp[t];
        }
        float sit = 0.f;
        #pragma unroll
        for (int t = 0; t < 8; ++t) {
            float4 qv = *(const float4*)&Qs[qloc][t * 4];
            sit = fmaf(kr[t].x, qv.x, sit);
            sit = fmaf(kr[t].y, qv.y, sit);
            sit = fmaf(kr[t].z, qv.z, sit);
            sit = fmaf(kr[t].w, qv.w, sit);
        }
        {
            const float4* kp = (const float4*)(KcG + (size_t)(kbase + kidx) * 32);
            #pragma unroll
            for (int t = 0; t < 8; ++t) kr[t] = kp[t];
        }
        float sct = 0.f;
        #pragma unroll
        for (int t = 0; t < 8; ++t) {
            float4 qv = *(const float4*)&Qs[qloc][32 + t * 4];
            sct = fmaf(kr[t].x, qv.x, sct);
            sct = fmaf(kr[t].y, qv.y, sct);
            sct = fmaf(kr[t].z, qv.z, sct);
            sct = fmaf(kr[t].w, qv.w, sct);
        }

        const float u = fmaf(a0, n0, sit);
        const float v = fmaf(a1, n1, sct);
        const int hsw = lj & 7;
        #pragma unroll
        for (int h = 0; h < H_; ++h) {
            float sc = fmaf(u, w0s[h], fmaf(v, w1s[h], bhs[h]));
            float p = kmb ? __expf(sc) : 0.f;
            l_reg[h] += p;
            Ps[w][lj][h ^ hsw][half] = p;          // swizzled transpose
        }
        __syncthreads();                            // Vb staged + Ps visible

        // ---- PV phase: lane owns (head hl, dims d0..d0+3), both queries ----
        #pragma unroll 8
        for (int j = 0; j < KB; ++j) {
            const float2 pp = *(const float2*)&Ps[w][j][hl ^ (j & 7)][0];
            ushort4 vb4 = *(const ushort4*)&Vb[j][hl * 32 + d0];
            const float vx = bf2f(vb4.x), vy = bf2f(vb4.y);
            const float vz = bf2f(vb4.z), vw = bf2f(vb4.w);
            acc0[0] = fmaf(pp.x, vx, acc0[0]); acc0[1] = fmaf(pp.x, vy, acc0[1]);
            acc0[2] = fmaf(pp.x, vz, acc0[2]); acc0[3] = fmaf(pp.x, vw, acc0[3]);
            acc1[0] = fmaf(pp.y, vx, acc1[0]); acc1[1] = fmaf(pp.y, vy, acc1[1]);
            acc1[2] = fmaf(pp.y, vz, acc1[2]); acc1[3] = fmaf(pp.y, vw, acc1[3]);
        }
        __syncthreads();                            // protect Vb/Ps for next chunk
    }

    // ---- denominator: butterfly sum within each 32-lane half ----
    #pragma unroll
    for (int h = 0; h < H_; ++h) {
        float lv = l_reg[h];
        #pragma unroll
        for (int d = 1; d < 32; d <<= 1) lv += __shfl_xor(lv, d, 64);
        l_reg[h] = lv;
    }
    const size_t obase = ((size_t)kz * B_ + b) * LQ_;
    if (lj == 0) {
        float* lp = ws_out + OFF_LP;
        #pragma unroll
        for (int h = 0; h < H_; ++h) lp[(obase + q) * 8 + h] = l_reg[h];
    }

    // ---- store bf16 partial numerators (PV layout) ----
    unsigned short* ob = (unsigned short*)(ws_out + OFF_OUTP);
    {
        const int qq = q0 + w * 2;
        ushort4 o0, o1;
        o0.x = f2bf(acc0[0]); o0.y = f2bf(acc0[1]); o0.z = f2bf(acc0[2]); o0.w = f2bf(acc0[3]);
        o1.x = f2bf(acc1[0]); o1.y = f2bf(acc1[1]); o1.z = f2bf(acc1[2]); o1.w = f2bf(acc1[3]);
        *(ushort4*)&ob[(obase + qq)     * 256 + hl * 32 + d0] = o0;
        *(ushort4*)&ob[(obase + qq + 1) * 256 + hl * 32 + d0] = o1;
    }
}

// ---------------------------------------------------------------------------
// Combine the 2 key-split partials: out = resid + qmask * (n0+n1)/(l0+l1)
// ---------------------------------------------------------------------------
__global__ __launch_bounds__(256)
void combine_kernel(const float* __restrict__ ws,
                    const float* __restrict__ resid,
                    const int* __restrict__ query_mask,
                    float* __restrict__ out)
{
    int idx = blockIdx.x * 256 + threadIdx.x;      // 0..262143
    int b   = idx >> 17;
    int rem = idx & 131071;
    int q   = rem >> 6;
    int c4  = (rem & 63) * 4;
    int h   = c4 >> 5;
    const unsigned short* ob = (const unsigned short*)(ws + OFF_OUTP);
    const float* lp = ws + OFF_LP;

    float l = lp[((size_t)b * LQ_ + q) * 8 + h]
            + lp[(((size_t)B_ + b) * LQ_ + q) * 8 + h];
    float qm = (float)query_mask[b * LQ_ + q];
    float sc = (l > 0.f) ? (qm / l) : 0.f;

    ushort4 u0 = *(const ushort4*)&ob[((size_t)b * LQ_ + q) * 256 + c4];
    ushort4 u1 = *(const ushort4*)&ob[(((size_t)B_ + b) * LQ_ + q) * 256 + c4];
    const size_t o = ((size_t)b * LQ_ + q) * 256 + c4;
    float4 r = *(const float4*)&resid[o];
    r.x = fmaf(bf2f(u0.x) + bf2f(u1.x), sc, r.x);
    r.y = fmaf(bf2f(u0.y) + bf2f(u1.y), sc, r.y);
    r.z = fmaf(bf2f(u0.z) + bf2f(u1.z), sc, r.z);
    r.w = fmaf(bf2f(u0.w) + bf2f(u1.w), sc, r.w);
    *(float4*)&out[o] = r;
}

// ---------------------------------------------------------------------------
extern "C" void kernel_launch(void* const* d_in, const int* in_sizes, int n_in,
                              void* d_out, int out_size, void* d_ws, size_t ws_size,
                              hipStream_t stream)
{
    (void)in_sizes; (void)n_in; (void)out_size; (void)ws_size;
    const float* queries_it  = (const float*)d_in[0];
    const float* queries_ctx = (const float*)d_in[1];
    const float* keys_it     = (const float*)d_in[2];
    const float* keys_ctx    = (const float*)d_in[3];
    const float* sigma       = (const float*)d_in[4];
    const float* noise       = (const float*)d_in[5];
    const float* Wq_it       = (const float*)d_in[6];
    const float* Wk_it       = (const float*)d_in[7];
    const float* Wq_ctx      = (const float*)d_in[8];
    const float* Wk_ctx      = (const float*)d_in[9];
    const float* Wv          = (const float*)d_in[10];
    const float* W_hdp       = (const float*)d_in[11];
    const float* b_hdp       = (const float*)d_in[12];
    const int*   key_mask    = (const int*)d_in[13];
    const int*   query_mask  = (const int*)d_in[14];
    float* out = (float*)d_out;
    float* ws  = (float*)d_ws;    // needs 8.65 MB

    proj_qk_kernel<<<dim3(2048), dim3(256), 0, stream>>>(
        queries_it, queries_ctx, keys_it, keys_ctx,
        Wq_it, Wq_ctx, Wk_it, Wk_ctx, ws);

    proj_v_kernel<<<dim3(1024), dim3(256), 0, stream>>>(
        keys_it, Wv, (unsigned short*)(ws + OFF_VB));

    attn_kernel<<<dim3(LQ_ / QB, KSPLIT * B_), dim3(256), 0, stream>>>(
        ws, sigma, noise, W_hdp, b_hdp, key_mask, ws);

    combine_kernel<<<dim3(1024), dim3(256), 0, stream>>>(
        ws, queries_it, query_mask, out);
}

// Round 4
// 426.704 us; speedup vs baseline: 1.0384x; 1.0384x over previous
//
#include <hip/hip_runtime.h>
#include <hip/hip_bf16.h>
#include <cstddef>
#include <cstdint>

#define B_   2
#define LQ_  2048
#define LK_  2048
#define H_   8
#define QB   8       // queries per block
#define KB   32      // keys per chunk
#define NW   4       // waves per block
#define KSPLIT 2
#define KEYS_PER_SPLIT (LK_/KSPLIT)   // 1024
#define NCH (KEYS_PER_SPLIT/KB)       // 32 chunks per block

// ws layout (float slot offsets)
#define OFF_QIT  0
#define OFF_QC   131072
#define OFF_KIT  262144
#define OFF_KC   393216
#define OFF_VB   524288      // ushort[B*LK*256] bf16 V  (524288 float slots)
#define OFF_OUTP 1048576     // ushort[KSPLIT*B*LQ*256] bf16 partial out
#define OFF_LP   2097152     // float[KSPLIT*B*LQ*8] partial denominators
// total 2162688 floats = 8.65 MB

__device__ __forceinline__ unsigned short f2bf(float f) {
    unsigned int x = __float_as_uint(f);
    unsigned int r = x + 0x7FFFu + ((x >> 16) & 1u);   // round-to-nearest-even
    return (unsigned short)(r >> 16);
}
__device__ __forceinline__ float bf2f(unsigned short u) {
    return __uint_as_float(((unsigned int)u) << 16);
}

// ---------------------------------------------------------------------------
// Fused small projections: Qit, Qc, Kit, Kc  (all [4096 rows] x 32 cols)
// ---------------------------------------------------------------------------
__global__ __launch_bounds__(256)
void proj_qk_kernel(const float* __restrict__ Aq_it, const float* __restrict__ Aq_c,
                    const float* __restrict__ Ak_it, const float* __restrict__ Ak_c,
                    const float* __restrict__ Wq_it, const float* __restrict__ Wq_c,
                    const float* __restrict__ Wk_it, const float* __restrict__ Wk_c,
                    float* __restrict__ ws)
{
    int idx = blockIdx.x * 256 + threadIdx.x;
    int seg = idx >> 17;
    int off = idx & 131071;
    int r = off >> 5;
    int c = off & 31;
    const float* A; const float* W; int K; float* O;
    if (seg == 0)      { A = Aq_it; W = Wq_it; K = 256; O = ws + OFF_QIT; }
    else if (seg == 1) { A = Aq_c;  W = Wq_c;  K = 128; O = ws + OFF_QC;  }
    else if (seg == 2) { A = Ak_it; W = Wk_it; K = 256; O = ws + OFF_KIT; }
    else               { A = Ak_c;  W = Wk_c;  K = 128; O = ws + OFF_KC;  }
    const float* a = A + (size_t)r * K;
    float s = 0.f;
    #pragma unroll 8
    for (int k = 0; k < K; ++k)
        s = fmaf(a[k], W[k * 32 + c], s);
    O[off] = s;
}

// ---------------------------------------------------------------------------
// V projection: keys_it [4096,256] @ Wv [256,256] -> bf16 V [4096,256]
// 512 blocks x 8 rows. A-tile in LDS (wave-uniform broadcast reads);
// Wv streamed coalesced (each wave reads 1KB/k, L1/L2-cached).
// ---------------------------------------------------------------------------
__global__ __launch_bounds__(256)
void proj_v_kernel(const float* __restrict__ A, const float* __restrict__ Wv,
                   unsigned short* __restrict__ Vb)
{
    __shared__ float As[8][264];
    const int tid = threadIdx.x;
    const int r0 = blockIdx.x * 8;

    const float4* src = (const float4*)(A + (size_t)r0 * 256);
    #pragma unroll
    for (int i = 0; i < 2; ++i) {
        int idx = tid + 256 * i;                   // 0..511
        int row = idx >> 6, c4 = idx & 63;
        float4 v = src[idx];
        *(float4*)&As[row][c4 * 4] = v;
    }
    __syncthreads();

    const int rg = tid >> 6;                       // wave id -> rows rg*2, rg*2+1
    const int c4 = tid & 63;
    float acc0[4] = {0.f,0.f,0.f,0.f}, acc1[4] = {0.f,0.f,0.f,0.f};
    const float4* w4 = (const float4*)Wv;          // [256][64]
    #pragma unroll 4
    for (int k = 0; k < 256; ++k) {
        float a0 = As[rg * 2][k];
        float a1 = As[rg * 2 + 1][k];
        float4 wv = w4[(size_t)k * 64 + c4];
        acc0[0] = fmaf(a0, wv.x, acc0[0]); acc0[1] = fmaf(a0, wv.y, acc0[1]);
        acc0[2] = fmaf(a0, wv.z, acc0[2]); acc0[3] = fmaf(a0, wv.w, acc0[3]);
        acc1[0] = fmaf(a1, wv.x, acc1[0]); acc1[1] = fmaf(a1, wv.y, acc1[1]);
        acc1[2] = fmaf(a1, wv.z, acc1[2]); acc1[3] = fmaf(a1, wv.w, acc1[3]);
    }
    ushort4 o0, o1;
    o0.x = f2bf(acc0[0]); o0.y = f2bf(acc0[1]); o0.z = f2bf(acc0[2]); o0.w = f2bf(acc0[3]);
    o1.x = f2bf(acc1[0]); o1.y = f2bf(acc1[1]); o1.z = f2bf(acc1[2]); o1.w = f2bf(acc1[3]);
    *(ushort4*)&Vb[(size_t)(r0 + rg * 2)     * 256 + c4 * 4] = o0;
    *(ushort4*)&Vb[(size_t)(r0 + rg * 2 + 1) * 256 + c4 * 4] = o1;
}

// ---------------------------------------------------------------------------
// Fused dual-stream attention, no-max softmax, key-split partials,
// software-pipelined: noise/key_mask/V-stage loads for chunk ch+1 are issued
// right after B2 of chunk ch (consumed one full chunk later, so the implicit
// vmcnt(0) at each __syncthreads only waits on loads issued ~1 chunk ago).
// ---------------------------------------------------------------------------
__global__ __launch_bounds__(256, 4)
void attn_kernel(const float* __restrict__ ws,
                 const float* __restrict__ sigma,
                 const float* __restrict__ noise,
                 const float* __restrict__ Whdp,
                 const float* __restrict__ bhdp,
                 const int* __restrict__ key_mask,
                 float* __restrict__ ws_out)
{
    const int tid  = threadIdx.x;
    const int w    = tid >> 6;
    const int lane = tid & 63;
    const int half = lane >> 5;
    const int lj   = lane & 31;
    const int b    = blockIdx.y & 1;
    const int kz   = blockIdx.y >> 1;
    const int q0   = blockIdx.x * QB;
    const int qloc = w * 2 + half;                 // 0..7
    const int q    = q0 + qloc;
    const int hl   = lane >> 3;                    // PV head 0..7
    const int d0   = (lane & 7) * 4;               // PV dim group

    __shared__ float Qs[QB][68];
    __shared__ unsigned short Vb[KB][256];         // bf16, 16 KB
    __shared__ float Ps[NW][KB][H_][2];            // 8 KB

    const int kbase = kz * KEYS_PER_SPLIT;
    const float* KitG = ws + OFF_KIT + (size_t)b * LK_ * 32;
    const float* KcG  = ws + OFF_KC  + (size_t)b * LK_ * 32;
    const unsigned short* VbG = (const unsigned short*)(ws + OFF_VB) + (size_t)b * LK_ * 256;
    const float* n0p = noise + ((size_t)(b * 2 + 0) * LQ_ + q) * LK_ + kbase;
    const float* n1p = noise + ((size_t)(b * 2 + 1) * LQ_ + q) * LK_ + kbase;
    const int*   km  = key_mask + b * LK_ + kbase;
    const uint4* vsrc = (const uint4*)(VbG + (size_t)kbase * 256);   // 1024 uint4/chunk

    // ---- prologue prefetch for chunk 0 ----
    uint4 vpf0 = vsrc[tid], vpf1 = vsrc[tid + 256];
    uint4 vpf2 = vsrc[tid + 512], vpf3 = vsrc[tid + 768];
    float n0f = n0p[lj];
    float n1f = n1p[lj];
    int   kmf = km[lj];

    // ---- stage Q tile (8 rows x 64 floats: it | ctx) ----
    if (tid < 128) {
        int r = tid >> 4, t = tid & 15;
        int c = t * 4;
        float4 v;
        if (c < 32)
            v = *(const float4*)&ws[OFF_QIT + ((size_t)b * LQ_ + q0 + r) * 32 + c];
        else
            v = *(const float4*)&ws[OFF_QC + ((size_t)b * LQ_ + q0 + r) * 32 + (c - 32)];
        *(float4*)&Qs[r][c] = v;
    }

    const float s0 = sigma[b * 2 + 0], s1 = sigma[b * 2 + 1];
    const float a0 = s0 * s0, a1 = s1 * s1;
    const float rsd = 0.17677669529663687f;        // 1/sqrt(32)
    float w0s[H_], w1s[H_], bhs[H_];
    #pragma unroll
    for (int h = 0; h < H_; ++h) {
        w0s[h] = Whdp[h]      * rsd;
        w1s[h] = Whdp[H_ + h] * rsd;
        bhs[h] = bhdp[h]      * rsd;
    }

    float l_reg[H_];
    #pragma unroll
    for (int h = 0; h < H_; ++h) l_reg[h] = 0.f;
    float acc0[4] = {0.f,0.f,0.f,0.f}, acc1[4] = {0.f,0.f,0.f,0.f};

    const int hsw = (lj >> 1) & 7;                 // 2-way (free) Ps bank swizzle

    __syncthreads();                               // Qs ready

    for (int ch = 0; ch < NCH; ++ch) {
        const int kidx = ch * KB + lj;

        // ---- score phase (uses prefetched n0f/n1f/kmf; K from L2) ----
        float4 kr[8];
        {
            const float4* kp = (const float4*)(KitG + (size_t)(kbase + kidx) * 32);
            #pragma unroll
            for (int t = 0; t < 8; ++t) kr[t] = kp[t];
        }
        float sit = 0.f;
        #pragma unroll
        for (int t = 0; t < 8; ++t) {
            float4 qv = *(const float4*)&Qs[qloc][t * 4];
            sit = fmaf(kr[t].x, qv.x, sit);
            sit = fmaf(kr[t].y, qv.y, sit);
            sit = fmaf(kr[t].z, qv.z, sit);
            sit = fmaf(kr[t].w, qv.w, sit);
        }
        {
            const float4* kp = (const float4*)(KcG + (size_t)(kbase + kidx) * 32);
            #pragma unroll
            for (int t = 0; t < 8; ++t) kr[t] = kp[t];
        }
        float sct = 0.f;
        #pragma unroll
        for (int t = 0; t < 8; ++t) {
            float4 qv = *(const float4*)&Qs[qloc][32 + t * 4];
            sct = fmaf(kr[t].x, qv.x, sct);
            sct = fmaf(kr[t].y, qv.y, sct);
            sct = fmaf(kr[t].z, qv.z, sct);
            sct = fmaf(kr[t].w, qv.w, sct);
        }

        const float u = fmaf(a0, n0f, sit);
        const float v = fmaf(a1, n1f, sct);
        const bool kmb = kmf != 0;
        #pragma unroll
        for (int h = 0; h < H_; ++h) {
            float sc = fmaf(u, w0s[h], fmaf(v, w1s[h], bhs[h]));
            float p = kmb ? __expf(sc) : 0.f;
            l_reg[h] += p;
            Ps[w][lj][h ^ hsw][half] = p;          // wave-private transpose
        }

        __syncthreads();                           // B1: all waves done PV(ch-1)

        // ---- write V stage (from regs prefetched one chunk ago) ----
        {
            uint4* vdst = (uint4*)&Vb[0][0];
            vdst[tid]       = vpf0;
            vdst[tid + 256] = vpf1;
            vdst[tid + 512] = vpf2;
            vdst[tid + 768] = vpf3;
        }
        __syncthreads();                           // B2: Vb visible (vmcnt already 0)

        // ---- issue prefetch for chunk ch+1 (in flight across PV + next score) ----
        if (ch + 1 < NCH) {
            const uint4* vn = vsrc + (size_t)(ch + 1) * 1024;
            vpf0 = vn[tid];       vpf1 = vn[tid + 256];
            vpf2 = vn[tid + 512]; vpf3 = vn[tid + 768];
            n0f = n0p[kidx + KB];
            n1f = n1p[kidx + KB];
            kmf = km[kidx + KB];
        }

        // ---- PV phase: lane owns (head hl, dims d0..d0+3), both queries ----
        #pragma unroll 8
        for (int j = 0; j < KB; ++j) {
            const float2 pp = *(const float2*)&Ps[w][j][hl ^ ((j >> 1) & 7)][0];
            ushort4 vb4 = *(const ushort4*)&Vb[j][hl * 32 + d0];
            const float vx = bf2f(vb4.x), vy = bf2f(vb4.y);
            const float vz = bf2f(vb4.z), vw = bf2f(vb4.w);
            acc0[0] = fmaf(pp.x, vx, acc0[0]); acc0[1] = fmaf(pp.x, vy, acc0[1]);
            acc0[2] = fmaf(pp.x, vz, acc0[2]); acc0[3] = fmaf(pp.x, vw, acc0[3]);
            acc1[0] = fmaf(pp.y, vx, acc1[0]); acc1[1] = fmaf(pp.y, vy, acc1[1]);
            acc1[2] = fmaf(pp.y, vz, acc1[2]); acc1[3] = fmaf(pp.y, vw, acc1[3]);
        }
    }

    // ---- denominator: butterfly sum within each 32-lane half ----
    #pragma unroll
    for (int h = 0; h < H_; ++h) {
        float lv = l_reg[h];
        #pragma unroll
        for (int d = 1; d < 32; d <<= 1) lv += __shfl_xor(lv, d, 64);
        l_reg[h] = lv;
    }
    const size_t obase = ((size_t)kz * B_ + b) * LQ_;
    if (lj == 0) {
        float* lp = ws_out + OFF_LP;
        #pragma unroll
        for (int h = 0; h < H_; ++h) lp[(obase + q) * 8 + h] = l_reg[h];
    }

    // ---- store bf16 partial numerators (PV layout) ----
    unsigned short* ob = (unsigned short*)(ws_out + OFF_OUTP);
    {
        const int qq = q0 + w * 2;
        ushort4 o0, o1;
        o0.x = f2bf(acc0[0]); o0.y = f2bf(acc0[1]); o0.z = f2bf(acc0[2]); o0.w = f2bf(acc0[3]);
        o1.x = f2bf(acc1[0]); o1.y = f2bf(acc1[1]); o1.z = f2bf(acc1[2]); o1.w = f2bf(acc1[3]);
        *(ushort4*)&ob[(obase + qq)     * 256 + hl * 32 + d0] = o0;
        *(ushort4*)&ob[(obase + qq + 1) * 256 + hl * 32 + d0] = o1;
    }
}

// ---------------------------------------------------------------------------
// Combine the 2 key-split partials: out = resid + qmask * (n0+n1)/(l0+l1)
// ---------------------------------------------------------------------------
__global__ __launch_bounds__(256)
void combine_kernel(const float* __restrict__ ws,
                    const float* __restrict__ resid,
                    const int* __restrict__ query_mask,
                    float* __restrict__ out)
{
    int idx = blockIdx.x * 256 + threadIdx.x;      // 0..262143
    int b   = idx >> 17;
    int rem = idx & 131071;
    int q   = rem >> 6;
    int c4  = (rem & 63) * 4;
    int h   = c4 >> 5;
    const unsigned short* ob = (const unsigned short*)(ws + OFF_OUTP);
    const float* lp = ws + OFF_LP;

    float l = lp[((size_t)b * LQ_ + q) * 8 + h]
            + lp[(((size_t)B_ + b) * LQ_ + q) * 8 + h];
    float qm = (float)query_mask[b * LQ_ + q];
    float sc = (l > 0.f) ? (qm / l) : 0.f;

    ushort4 u0 = *(const ushort4*)&ob[((size_t)b * LQ_ + q) * 256 + c4];
    ushort4 u1 = *(const ushort4*)&ob[(((size_t)B_ + b) * LQ_ + q) * 256 + c4];
    const size_t o = ((size_t)b * LQ_ + q) * 256 + c4;
    float4 r = *(const float4*)&resid[o];
    r.x = fmaf(bf2f(u0.x) + bf2f(u1.x), sc, r.x);
    r.y = fmaf(bf2f(u0.y) + bf2f(u1.y), sc, r.y);
    r.z = fmaf(bf2f(u0.z) + bf2f(u1.z), sc, r.z);
    r.w = fmaf(bf2f(u0.w) + bf2f(u1.w), sc, r.w);
    *(float4*)&out[o] = r;
}

// ---------------------------------------------------------------------------
extern "C" void kernel_launch(void* const* d_in, const int* in_sizes, int n_in,
                              void* d_out, int out_size, void* d_ws, size_t ws_size,
                              hipStream_t stream)
{
    (void)in_sizes; (void)n_in; (void)out_size; (void)ws_size;
    const float* queries_it  = (const float*)d_in[0];
    const float* queries_ctx = (const float*)d_in[1];
    const float* keys_it     = (const float*)d_in[2];
    const float* keys_ctx    = (const float*)d_in[3];
    const float* sigma       = (const float*)d_in[4];
    const float* noise       = (const float*)d_in[5];
    const float* Wq_it       = (const float*)d_in[6];
    const float* Wk_it       = (const float*)d_in[7];
    const float* Wq_ctx      = (const float*)d_in[8];
    const float* Wk_ctx      = (const float*)d_in[9];
    const float* Wv          = (const float*)d_in[10];
    const float* W_hdp       = (const float*)d_in[11];
    const float* b_hdp       = (const float*)d_in[12];
    const int*   key_mask    = (const int*)d_in[13];
    const int*   query_mask  = (const int*)d_in[14];
    float* out = (float*)d_out;
    float* ws  = (float*)d_ws;    // needs 8.65 MB

    proj_qk_kernel<<<dim3(2048), dim3(256), 0, stream>>>(
        queries_it, queries_ctx, keys_it, keys_ctx,
        Wq_it, Wq_ctx, Wk_it, Wk_ctx, ws);

    proj_v_kernel<<<dim3(512), dim3(256), 0, stream>>>(
        keys_it, Wv, (unsigned short*)(ws + OFF_VB));

    attn_kernel<<<dim3(LQ_ / QB, KSPLIT * B_), dim3(256), 0, stream>>>(
        ws, sigma, noise, W_hdp, b_hdp, key_mask, ws);

    combine_kernel<<<dim3(1024), dim3(256), 0, stream>>>(
        ws, queries_it, query_mask, out);
}

// Round 6
// 324.727 us; speedup vs baseline: 1.3644x; 1.3140x over previous
//
#include <hip/hip_runtime.h>
#include <hip/hip_bf16.h>
#include <cstddef>
#include <cstdint>

#define B_   2
#define LQ_  2048
#define LK_  2048
#define H_   8
#define NW   4
#define KSPLIT 4

// ws float-slot offsets
#define OFF_QB   0          // ushort[2*64*2*2*64*8]  = 262144 sh = 131072 f
#define OFF_KA   131072     // ushort[262144]
#define OFF_VA   262144     // ushort[1048576]        = 524288 f
#define OFF_NUM  786432     // float[B*LQ*256]        = 1048576 f
#define OFF_L    1835008    // float[B*LQ*8]          = 32768 f
// total 1867776 floats = 7.47 MB

typedef short  short8  __attribute__((ext_vector_type(8)));
typedef float  f32x16  __attribute__((ext_vector_type(16)));
typedef int    int2v   __attribute__((ext_vector_type(2)));

__device__ __forceinline__ unsigned short f2bf(float f) {
    unsigned int x = __float_as_uint(f);
    unsigned int r = x + 0x7FFFu + ((x >> 16) & 1u);
    return (unsigned short)(r >> 16);
}
__device__ __forceinline__ unsigned int cvtpk(float lo, float hi) {
    unsigned int r;
    asm("v_cvt_pk_bf16_f32 %0, %1, %2" : "=v"(r) : "v"(lo), "v"(hi));
    return r;
}

// ---------------------------------------------------------------------------
// init: zero num + l partial buffers (ws is poisoned 0xAA before each call)
// ---------------------------------------------------------------------------
__global__ __launch_bounds__(256)
void init_kernel(float* __restrict__ ws)
{
    int i = blockIdx.x * 256 + threadIdx.x;        // 0..270335 (f4 units)
    float4 z = {0.f, 0.f, 0.f, 0.f};
    *(float4*)&ws[OFF_NUM + (size_t)i * 4] = z;    // covers NUM then L (contiguous)
}

// ---------------------------------------------------------------------------
// proj_qk: Qit,Qc,Kit,Kc projections -> bf16 MFMA fragment layouts
//  QB[b][qblk][s][st][lane][8] = Q_s[b][qblk*32+(l&31)][16*st+8*(l>>5)+j]
//  KA identical for K. 131072 threads; thread = (entity, row, 4 cols).
// ---------------------------------------------------------------------------
__global__ __launch_bounds__(256)
void proj_qk_kernel(const float* __restrict__ Aq_it, const float* __restrict__ Aq_c,
                    const float* __restrict__ Ak_it, const float* __restrict__ Ak_c,
                    const float* __restrict__ Wq_it, const float* __restrict__ Wq_c,
                    const float* __restrict__ Wk_it, const float* __restrict__ Wk_c,
                    float* __restrict__ ws)
{
    int g   = blockIdx.x * 256 + threadIdx.x;      // 0..131071
    int ent = g >> 15;                             // 0=Qit 1=Qc 2=Kit 3=Kc
    int off = g & 32767;
    int r   = off >> 3;                            // global row 0..4095
    int c0  = (off & 7) * 4;                       // dim group
    const float* A; const float* W; int K;
    if (ent == 0)      { A = Aq_it; W = Wq_it; K = 256; }
    else if (ent == 1) { A = Aq_c;  W = Wq_c;  K = 128; }
    else if (ent == 2) { A = Ak_it; W = Wk_it; K = 256; }
    else               { A = Ak_c;  W = Wk_c;  K = 128; }

    const float* a = A + (size_t)r * K;
    float acc[4] = {0.f, 0.f, 0.f, 0.f};
    #pragma unroll 4
    for (int k = 0; k < K; ++k) {
        float av = a[k];
        float4 w4 = *(const float4*)&W[k * 32 + c0];
        acc[0] = fmaf(av, w4.x, acc[0]);
        acc[1] = fmaf(av, w4.y, acc[1]);
        acc[2] = fmaf(av, w4.z, acc[2]);
        acc[3] = fmaf(av, w4.w, acc[3]);
    }

    int s   = ent & 1;
    int b   = r >> 11;
    int row = r & 2047;
    int blk = row >> 5;
    int st  = c0 >> 4;
    int l   = (row & 31) + 32 * ((c0 >> 3) & 1);
    int j   = c0 & 7;
    unsigned short* dst = (unsigned short*)(ws + ((ent >> 1) ? OFF_KA : OFF_QB));
    size_t idx = ((size_t)(((b * 64 + blk) * 2 + s) * 2 + st) * 64 + l) * 8 + j;
    ushort4 o;
    o.x = f2bf(acc[0]); o.y = f2bf(acc[1]); o.z = f2bf(acc[2]); o.w = f2bf(acc[3]);
    *(ushort4*)&dst[idx] = o;
}

// ---------------------------------------------------------------------------
// proj_v: keys_it [4096,256] @ Wv [256,256] -> VA A-fragment layout bf16:
//  VA[b][kblk16][h][lane][8] = V[b][kblk16*16 + 8*(l>>5)+j][h*32 + (l&31)]
// ---------------------------------------------------------------------------
__global__ __launch_bounds__(256)
void proj_v_kernel(const float* __restrict__ A, const float* __restrict__ Wv,
                   float* __restrict__ ws)
{
    __shared__ float As[8][264];
    const int tid = threadIdx.x;
    const int r0  = blockIdx.x * 8;

    const float4* src = (const float4*)(A + (size_t)r0 * 256);
    #pragma unroll
    for (int i = 0; i < 2; ++i) {
        int idx = tid + 256 * i;
        int row = idx >> 6, c4i = idx & 63;
        *(float4*)&As[row][c4i * 4] = src[idx];
    }
    __syncthreads();

    const int rg = tid >> 6;
    const int c4 = tid & 63;
    float acc0[4] = {0.f,0.f,0.f,0.f}, acc1[4] = {0.f,0.f,0.f,0.f};
    const float4* w4p = (const float4*)Wv;
    #pragma unroll 4
    for (int k = 0; k < 256; ++k) {
        float a0 = As[rg * 2][k];
        float a1 = As[rg * 2 + 1][k];
        float4 wv = w4p[(size_t)k * 64 + c4];
        acc0[0] = fmaf(a0, wv.x, acc0[0]); acc0[1] = fmaf(a0, wv.y, acc0[1]);
        acc0[2] = fmaf(a0, wv.z, acc0[2]); acc0[3] = fmaf(a0, wv.w, acc0[3]);
        acc1[0] = fmaf(a1, wv.x, acc1[0]); acc1[1] = fmaf(a1, wv.y, acc1[1]);
        acc1[2] = fmaf(a1, wv.z, acc1[2]); acc1[3] = fmaf(a1, wv.w, acc1[3]);
    }

    unsigned short* va = (unsigned short*)(ws + OFF_VA);
    #pragma unroll
    for (int jr = 0; jr < 2; ++jr) {
        int rg2 = r0 + rg * 2 + jr;
        int b = rg2 >> 11, k = rg2 & 2047;
        size_t base = ((size_t)(b * 128 + (k >> 4)) * 8) * 512;
        int lhalf = 32 * ((k >> 3) & 1);
        int j = k & 7;
        const float* ac = jr ? acc1 : acc0;
        #pragma unroll
        for (int i = 0; i < 4; ++i) {
            int c = c4 * 4 + i;
            int h = c >> 5, d = c & 31;
            va[base + (size_t)h * 512 + (size_t)(d + lhalf) * 8 + j] = f2bf(ac[i]);
        }
    }
}

// ---------------------------------------------------------------------------
// attn: barrier-free MFMA attention. Block = 32 queries x 4 waves; wave owns
// 128 keys (4 chunks of 32). S^T = K·Q^T (mfma), noise reg-direct, P packed
// via cvt_pk + permlane32_swap, PV = V^T·P^T (mfma per head). Partials via
// coalesced fp32 atomicAdd (transposed through wave-private LDS).
// ---------------------------------------------------------------------------
__global__ __launch_bounds__(256, 2)
void attn_kernel(float* __restrict__ ws,
                 const float* __restrict__ sigma,
                 const float* __restrict__ noise,
                 const float* __restrict__ Whdp,
                 const float* __restrict__ bhdp,
                 const int* __restrict__ key_mask)
{
    const int tid  = threadIdx.x;
    const int w    = tid >> 6;
    const int lane = tid & 63;
    const int half = lane >> 5;
    const int lq   = lane & 31;
    const int b    = blockIdx.y & 1;
    const int kz   = blockIdx.y >> 1;
    const int q0   = blockIdx.x * 32;
    const int kstart = kz * (LK_ / KSPLIT) + w * 128;

    __shared__ float Nb[NW][32][33];

    const unsigned short* qkQB = (const unsigned short*)(ws + OFF_QB);
    const unsigned short* qkKA = (const unsigned short*)(ws + OFF_KA);
    const unsigned short* vaVA = (const unsigned short*)(ws + OFF_VA);
    float* wsnum = ws + OFF_NUM;
    float* wsl   = ws + OFF_L;

    // Q B-fragments (persistent, 16 VGPR)
    const unsigned short* qbp = qkQB + (size_t)((b * 64 + (q0 >> 5)) * 4) * 512;
    const short8 qb00 = *(const short8*)(qbp + 0 * 512 + lane * 8);
    const short8 qb01 = *(const short8*)(qbp + 1 * 512 + lane * 8);
    const short8 qb10 = *(const short8*)(qbp + 2 * 512 + lane * 8);
    const short8 qb11 = *(const short8*)(qbp + 3 * 512 + lane * 8);

    const float s0 = sigma[b * 2 + 0], s1 = sigma[b * 2 + 1];
    const float a0 = s0 * s0, a1 = s1 * s1;
    const float cvt = 0.17677669529663687f * 1.4426950408889634f; // /sqrt(32)*log2e
    float w0s[H_], w1s[H_], bh8[H_];
    #pragma unroll
    for (int h = 0; h < H_; ++h) {
        w0s[h] = Whdp[h]      * cvt;
        w1s[h] = Whdp[H_ + h] * cvt;
        bh8[h] = bhdp[h]      * cvt;
    }

    f32x16 acc[H_];
    float lacc[H_];
    #pragma unroll
    for (int h = 0; h < H_; ++h) { acc[h] = (f32x16)(0.0f); lacc[h] = 0.f; }

    const float* np0 = noise + ((size_t)(b * 2 + 0) * LQ_ + q0 + lq) * LK_;
    const float* np1 = noise + ((size_t)(b * 2 + 1) * LQ_ + q0 + lq) * LK_;

    for (int c = 0; c < 4; ++c) {
        const int k0 = kstart + c * 32;

        // ---- K A-fragments ----
        const unsigned short* kap = qkKA + (size_t)((b * 64 + (k0 >> 5)) * 4) * 512;
        short8 ka00 = *(const short8*)(kap + 0 * 512 + lane * 8);
        short8 ka01 = *(const short8*)(kap + 1 * 512 + lane * 8);
        short8 ka10 = *(const short8*)(kap + 2 * 512 + lane * 8);
        short8 ka11 = *(const short8*)(kap + 3 * 512 + lane * 8);

        // ---- S^T = K·Q^T per stream ----
        f32x16 zz = (f32x16)(0.0f);
        f32x16 sIT = __builtin_amdgcn_mfma_f32_32x32x16_bf16(ka00, qb00, zz, 0, 0, 0);
        sIT = __builtin_amdgcn_mfma_f32_32x32x16_bf16(ka01, qb01, sIT, 0, 0, 0);
        f32x16 sCT = __builtin_amdgcn_mfma_f32_32x32x16_bf16(ka10, qb10, zz, 0, 0, 0);
        sCT = __builtin_amdgcn_mfma_f32_32x32x16_bf16(ka11, qb11, sCT, 0, 0, 0);

        // ---- noise, reg-direct (reg 4rg+i <-> k = k0+8rg+4half+i) ----
        float u[16], v[16];
        #pragma unroll
        for (int rg = 0; rg < 4; ++rg) {
            float4 n0v = *(const float4*)&np0[k0 + 8 * rg + 4 * half];
            float4 n1v = *(const float4*)&np1[k0 + 8 * rg + 4 * half];
            u[rg*4+0] = fmaf(a0, n0v.x, sIT[rg*4+0]);
            u[rg*4+1] = fmaf(a0, n0v.y, sIT[rg*4+1]);
            u[rg*4+2] = fmaf(a0, n0v.z, sIT[rg*4+2]);
            u[rg*4+3] = fmaf(a0, n0v.w, sIT[rg*4+3]);
            v[rg*4+0] = fmaf(a1, n1v.x, sCT[rg*4+0]);
            v[rg*4+1] = fmaf(a1, n1v.y, sCT[rg*4+1]);
            v[rg*4+2] = fmaf(a1, n1v.z, sCT[rg*4+2]);
            v[rg*4+3] = fmaf(a1, n1v.w, sCT[rg*4+3]);
        }

        // ---- key mask per reg ----
        float kmv = (float)key_mask[b * LK_ + k0 + lq];
        float mva[16];
        #pragma unroll
        for (int r = 0; r < 16; ++r)
            mva[r] = __shfl(kmv, (r & 3) + 8 * (r >> 2) + 4 * half, 64);

        // ---- heads: p = exp2(u*w0+v*w1+b)*m ; pack; PV MFMA ----
        const unsigned short* vap = vaVA + (size_t)((b * 128 + (k0 >> 4)) * 8) * 512;
        #pragma unroll
        for (int h = 0; h < H_; ++h) {
            float p[16];
            #pragma unroll
            for (int r = 0; r < 16; ++r)
                p[r] = exp2f(fmaf(u[r], w0s[h], fmaf(v[r], w1s[h], bh8[h]))) * mva[r];
            lacc[h] += ((p[0]+p[1])+(p[2]+p[3])) + ((p[4]+p[5])+(p[6]+p[7]))
                     + ((p[8]+p[9])+(p[10]+p[11])) + ((p[12]+p[13])+(p[14]+p[15]));

            unsigned int pk0 = cvtpk(p[0], p[1]),  pk1 = cvtpk(p[2], p[3]);
            unsigned int pk2 = cvtpk(p[4], p[5]),  pk3 = cvtpk(p[6], p[7]);
            int2v sw0 = __builtin_amdgcn_permlane32_swap((int)pk0, (int)pk2, false, false);
            int2v sw1 = __builtin_amdgcn_permlane32_swap((int)pk1, (int)pk3, false, false);
            uint4 f0 = {(unsigned)sw0[0], (unsigned)sw1[0], (unsigned)sw0[1], (unsigned)sw1[1]};

            pk0 = cvtpk(p[8],  p[9]);   pk1 = cvtpk(p[10], p[11]);
            pk2 = cvtpk(p[12], p[13]);  pk3 = cvtpk(p[14], p[15]);
            int2v sw2 = __builtin_amdgcn_permlane32_swap((int)pk0, (int)pk2, false, false);
            int2v sw3 = __builtin_amdgcn_permlane32_swap((int)pk1, (int)pk3, false, false);
            uint4 f1 = {(unsigned)sw2[0], (unsigned)sw3[0], (unsigned)sw2[1], (unsigned)sw3[1]};

            short8 bf0 = *(short8*)&f0;
            short8 bf1 = *(short8*)&f1;
            short8 va0 = *(const short8*)(vap + (size_t)h * 512 + lane * 8);
            short8 va1 = *(const short8*)(vap + 4096 + (size_t)h * 512 + lane * 8);
            acc[h] = __builtin_amdgcn_mfma_f32_32x32x16_bf16(va0, bf0, acc[h], 0, 0, 0);
            acc[h] = __builtin_amdgcn_mfma_f32_32x32x16_bf16(va1, bf1, acc[h], 0, 0, 0);
        }
    }

    // ---- denominators: lane + other-half, then coalesced atomic ----
    float lsum[H_];
    #pragma unroll
    for (int h = 0; h < H_; ++h)
        lsum[h] = lacc[h] + __shfl_xor(lacc[h], 32, 64);
    if (lane < 32) {
        #pragma unroll
        for (int h = 0; h < H_; ++h)
            atomicAdd(&wsl[((size_t)b * LQ_ + q0 + lq) * 8 + h], lsum[h]);
    }

    // ---- numerators: transpose C-layout via wave-private LDS, atomic ----
    float* nb = &Nb[w][0][0];
    #pragma unroll
    for (int h = 0; h < H_; ++h) {
        #pragma unroll
        for (int r = 0; r < 16; ++r) {
            int d = (r & 3) + 8 * (r >> 2) + 4 * half;
            nb[d * 33 + lq] = acc[h][r];
        }
        #pragma unroll
        for (int i = 0; i < 16; ++i) {
            int q = 2 * i + half;
            float val = nb[lq * 33 + q];
            atomicAdd(&wsnum[((size_t)b * LQ_ + q0 + q) * 256 + h * 32 + lq], val);
        }
    }
}

// ---------------------------------------------------------------------------
// combine: out = resid + qmask * num / l
// ---------------------------------------------------------------------------
__global__ __launch_bounds__(256)
void combine_kernel(const float* __restrict__ ws,
                    const float* __restrict__ resid,
                    const int* __restrict__ query_mask,
                    float* __restrict__ out)
{
    int idx = blockIdx.x * 256 + threadIdx.x;      // 0..262143
    int b   = idx >> 17;
    int rem = idx & 131071;
    int q   = rem >> 6;
    int c4  = (rem & 63) * 4;
    int h   = c4 >> 5;

    float l  = ws[OFF_L + ((size_t)b * LQ_ + q) * 8 + h];
    float qm = (float)query_mask[b * LQ_ + q];
    float sc = (l > 0.f) ? (qm / l) : 0.f;

    float4 n = *(const float4*)&ws[OFF_NUM + ((size_t)b * LQ_ + q) * 256 + c4];
    const size_t o = ((size_t)b * LQ_ + q) * 256 + c4;
    float4 r = *(const float4*)&resid[o];
    r.x = fmaf(n.x, sc, r.x);
    r.y = fmaf(n.y, sc, r.y);
    r.z = fmaf(n.z, sc, r.z);
    r.w = fmaf(n.w, sc, r.w);
    *(float4*)&out[o] = r;
}

// ---------------------------------------------------------------------------
extern "C" void kernel_launch(void* const* d_in, const int* in_sizes, int n_in,
                              void* d_out, int out_size, void* d_ws, size_t ws_size,
                              hipStream_t stream)
{
    (void)in_sizes; (void)n_in; (void)out_size; (void)ws_size;
    const float* queries_it  = (const float*)d_in[0];
    const float* queries_ctx = (const float*)d_in[1];
    const float* keys_it     = (const float*)d_in[2];
    const float* keys_ctx    = (const float*)d_in[3];
    const float* sigma       = (const float*)d_in[4];
    const float* noise       = (const float*)d_in[5];
    const float* Wq_it       = (const float*)d_in[6];
    const float* Wk_it       = (const float*)d_in[7];
    const float* Wq_ctx      = (const float*)d_in[8];
    const float* Wk_ctx      = (const float*)d_in[9];
    const float* Wv          = (const float*)d_in[10];
    const float* W_hdp       = (const float*)d_in[11];
    const float* b_hdp       = (const float*)d_in[12];
    const int*   key_mask    = (const int*)d_in[13];
    const int*   query_mask  = (const int*)d_in[14];
    float* out = (float*)d_out;
    float* ws  = (float*)d_ws;    // needs 7.47 MB

    init_kernel<<<dim3(1056), dim3(256), 0, stream>>>(ws);

    proj_qk_kernel<<<dim3(512), dim3(256), 0, stream>>>(
        queries_it, queries_ctx, keys_it, keys_ctx,
        Wq_it, Wq_ctx, Wk_it, Wk_ctx, ws);

    proj_v_kernel<<<dim3(512), dim3(256), 0, stream>>>(keys_it, Wv, ws);

    attn_kernel<<<dim3(LQ_ / 32, KSPLIT * B_), dim3(256), 0, stream>>>(
        ws, sigma, noise, W_hdp, b_hdp, key_mask);

    combine_kernel<<<dim3(1024), dim3(256), 0, stream>>>(
        ws, queries_it, query_mask, out);
}

// Round 7
// 229.033 us; speedup vs baseline: 1.9345x; 1.4178x over previous
//
#include <hip/hip_runtime.h>
#include <hip/hip_bf16.h>
#include <cstddef>
#include <cstdint>

#define B_   2
#define LQ_  2048
#define LK_  2048
#define H_   8

// ws float-slot offsets (total 786432 floats = 3 MB)
#define OFF_QB 0          // ushort[2*128*2*64*8] = 262144 ush
#define OFF_KA 131072     // ushort[262144]
#define OFF_VA 262144     // ushort[2*64*8*2*64*8] = 1048576 ush

typedef short  short8 __attribute__((ext_vector_type(8)));
typedef float  f32x4  __attribute__((ext_vector_type(4)));
typedef int    int2v  __attribute__((ext_vector_type(2)));

__device__ __forceinline__ unsigned short f2bf(float f) {
    unsigned int x = __float_as_uint(f);
    unsigned int r = x + 0x7FFFu + ((x >> 16) & 1u);   // RNE
    return (unsigned short)(r >> 16);
}
__device__ __forceinline__ unsigned int cvtpk(float lo, float hi) {
    unsigned int r;
    asm("v_cvt_pk_bf16_f32 %0, %1, %2" : "=v"(r) : "v"(lo), "v"(hi));
    return r;
}

// ---------------------------------------------------------------------------
// proj_qk: Qit,Qc,Kit,Kc -> bf16 16x16x32-MFMA fragment layout:
//  frag[b][blk16][s][lane][j] = X_s[b][blk16*16 + (lane&15)][8*(lane>>4)+j]
// ---------------------------------------------------------------------------
__global__ __launch_bounds__(256)
void proj_qk_kernel(const float* __restrict__ Aq_it, const float* __restrict__ Aq_c,
                    const float* __restrict__ Ak_it, const float* __restrict__ Ak_c,
                    const float* __restrict__ Wq_it, const float* __restrict__ Wq_c,
                    const float* __restrict__ Wk_it, const float* __restrict__ Wk_c,
                    float* __restrict__ ws)
{
    int g   = blockIdx.x * 256 + threadIdx.x;      // 0..131071
    int ent = g >> 15;                             // 0=Qit 1=Qc 2=Kit 3=Kc
    int off = g & 32767;
    int r   = off >> 3;                            // global row 0..4095
    int c0  = (off & 7) * 4;                       // dim group (0,4,..,28)
    const float* A; const float* W; int K;
    if (ent == 0)      { A = Aq_it; W = Wq_it; K = 256; }
    else if (ent == 1) { A = Aq_c;  W = Wq_c;  K = 128; }
    else if (ent == 2) { A = Ak_it; W = Wk_it; K = 256; }
    else               { A = Ak_c;  W = Wk_c;  K = 128; }

    const float* a = A + (size_t)r * K;
    float acc[4] = {0.f, 0.f, 0.f, 0.f};
    #pragma unroll 4
    for (int k = 0; k < K; ++k) {
        float av = a[k];
        float4 w4 = *(const float4*)&W[k * 32 + c0];
        acc[0] = fmaf(av, w4.x, acc[0]);
        acc[1] = fmaf(av, w4.y, acc[1]);
        acc[2] = fmaf(av, w4.z, acc[2]);
        acc[3] = fmaf(av, w4.w, acc[3]);
    }

    int s    = ent & 1;
    int bb   = r >> 11;
    int row  = r & 2047;
    int lane = (row & 15) + 16 * (c0 >> 3);
    int j    = c0 & 7;                             // 0 or 4
    unsigned short* dst = (unsigned short*)(ws + ((ent >> 1) ? OFF_KA : OFF_QB));
    size_t idx = ((size_t)(((bb * 128 + (row >> 4)) * 2 + s) * 64 + lane)) * 8 + j;
    ushort4 o;
    o.x = f2bf(acc[0]); o.y = f2bf(acc[1]); o.z = f2bf(acc[2]); o.w = f2bf(acc[3]);
    *(ushort4*)&dst[idx] = o;
}

// ---------------------------------------------------------------------------
// proj_v: keys_it [4096,256] @ Wv -> VA bf16 A-frag layout:
//  VA[b][kblk32][h][dh][lane][j] = V[b][kblk*32 + 8*(lane>>4)+j][h*32+dh*16+(lane&15)]
// Block = (b, kblk, half of 4 heads): compute -> LDS tile -> coalesced writes.
// ---------------------------------------------------------------------------
__global__ __launch_bounds__(256)
void proj_v_kernel(const float* __restrict__ A, const float* __restrict__ Wv,
                   float* __restrict__ ws)
{
    __shared__ float Vt[32][132];
    const int bx   = blockIdx.x;                   // 0..255
    const int b    = bx >> 7, kblk = (bx >> 1) & 63, half = bx & 1;
    const int tid  = threadIdx.x;
    const int kk   = tid >> 3, ci = tid & 7;

    const float* a = A + ((size_t)(b * 2048 + kblk * 32 + kk)) * 256;
    const float* wbase = Wv + half * 128 + ci * 4;
    float4 acc[4];
    #pragma unroll
    for (int ii = 0; ii < 4; ++ii) acc[ii] = make_float4(0.f, 0.f, 0.f, 0.f);
    for (int k = 0; k < 256; ++k) {
        float av = a[k];
        #pragma unroll
        for (int ii = 0; ii < 4; ++ii) {
            float4 wv = *(const float4*)&wbase[(size_t)k * 256 + 32 * ii];
            acc[ii].x = fmaf(av, wv.x, acc[ii].x);
            acc[ii].y = fmaf(av, wv.y, acc[ii].y);
            acc[ii].z = fmaf(av, wv.z, acc[ii].z);
            acc[ii].w = fmaf(av, wv.w, acc[ii].w);
        }
    }
    #pragma unroll
    for (int ii = 0; ii < 4; ++ii)
        *(float4*)&Vt[kk][ci * 4 + 32 * ii] = acc[ii];
    __syncthreads();

    unsigned short* va = (unsigned short*)(ws + OFF_VA);
    const size_t base = (size_t)(b * 64 + kblk) * 8192 + half * 4096;
    #pragma unroll
    for (int pass = 0; pass < 2; ++pass) {
        int o   = pass * 2048 + tid * 8;
        int hp  = o >> 10, rem = o & 1023;
        int dh  = rem >> 9, l6 = (rem >> 3) & 63;
        int m   = l6 & 15, kq = l6 >> 4;
        int ld  = hp * 32 + dh * 16 + m;
        unsigned int d0 = (unsigned)f2bf(Vt[kq * 8 + 0][ld]) | ((unsigned)f2bf(Vt[kq * 8 + 1][ld]) << 16);
        unsigned int d1 = (unsigned)f2bf(Vt[kq * 8 + 2][ld]) | ((unsigned)f2bf(Vt[kq * 8 + 3][ld]) << 16);
        unsigned int d2 = (unsigned)f2bf(Vt[kq * 8 + 4][ld]) | ((unsigned)f2bf(Vt[kq * 8 + 5][ld]) << 16);
        unsigned int d3 = (unsigned)f2bf(Vt[kq * 8 + 6][ld]) | ((unsigned)f2bf(Vt[kq * 8 + 7][ld]) << 16);
        uint4 pack = {d0, d1, d2, d3};
        *(uint4*)&va[base + o] = pack;
    }
}

// ---------------------------------------------------------------------------
// attn: fully fused. Block = 16 queries x 2048 keys, 8 waves x 256 keys.
// 16x16x32 MFMA, noise reg-direct, P via cvt_pk + permlane32_swap + xor16
// ds_swizzle, cross-wave LDS reduce, direct out write. No atomics, no combine.
// ---------------------------------------------------------------------------
__global__ __launch_bounds__(512, 2)
void attn_kernel(const float* __restrict__ ws,
                 const float* __restrict__ resid,
                 const float* __restrict__ sigma,
                 const float* __restrict__ noise,
                 const float* __restrict__ Whdp,
                 const float* __restrict__ bhdp,
                 const int* __restrict__ key_mask,
                 const int* __restrict__ query_mask,
                 float* __restrict__ out)
{
    __shared__ float Nb[8][32][18];
    __shared__ float Ls[8][16][9];
    __shared__ float Linv[16][9];

    const int tid  = threadIdx.x;
    const int w    = tid >> 6, lane = tid & 63;
    const int q16  = lane & 15, qq = lane >> 4;
    const int b    = blockIdx.y;
    const int q0   = blockIdx.x * 16;
    const int kw   = w * 256;

    const unsigned short* QBp = (const unsigned short*)(ws + OFF_QB);
    const unsigned short* KAp = (const unsigned short*)(ws + OFF_KA);
    const unsigned short* VAp = (const unsigned short*)(ws + OFF_VA);

    const short8 qb0 = *(const short8*)(QBp + ((size_t)((b * 128 + (q0 >> 4)) * 2 + 0)) * 512 + lane * 8);
    const short8 qb1 = *(const short8*)(QBp + ((size_t)((b * 128 + (q0 >> 4)) * 2 + 1)) * 512 + lane * 8);

    const float s0 = sigma[b * 2 + 0], s1 = sigma[b * 2 + 1];
    const float a0 = s0 * s0, a1 = s1 * s1;
    const float cvt = 0.17677669529663687f * 1.4426950408889634f; // 1/sqrt(32)*log2(e)
    float w0s[H_], w1s[H_], bh8[H_];
    #pragma unroll
    for (int h = 0; h < H_; ++h) {
        w0s[h] = Whdp[h]      * cvt;
        w1s[h] = Whdp[H_ + h] * cvt;
        bh8[h] = bhdp[h]      * cvt;
    }

    f32x4 acc[H_][2];
    float lacc[H_];
    #pragma unroll
    for (int h = 0; h < H_; ++h) {
        acc[h][0] = (f32x4){0.f, 0.f, 0.f, 0.f};
        acc[h][1] = (f32x4){0.f, 0.f, 0.f, 0.f};
        lacc[h] = 0.f;
    }

    const float* np0 = noise + ((size_t)(b * 2 + 0) * LQ_ + q0 + q16) * LK_;
    const float* np1 = noise + ((size_t)(b * 2 + 1) * LQ_ + q0 + q16) * LK_;
    const int*   kmp = key_mask + b * LK_;

    // ---- prefetch chunk 0 ----
    short8 kaA[4]; float4 nfA[4]; int4 kmA[2];
    {
        const int k0 = kw;
        const unsigned short* kap = KAp + (size_t)(b * 128 + (k0 >> 4)) * 1024;
        #pragma unroll
        for (int gg = 0; gg < 2; ++gg)
            #pragma unroll
            for (int ss = 0; ss < 2; ++ss)
                kaA[gg * 2 + ss] = *(const short8*)(kap + gg * 1024 + ss * 512 + lane * 8);
        nfA[0] = *(const float4*)&np0[k0 + 4 * qq];
        nfA[1] = *(const float4*)&np0[k0 + 16 + 4 * qq];
        nfA[2] = *(const float4*)&np1[k0 + 4 * qq];
        nfA[3] = *(const float4*)&np1[k0 + 16 + 4 * qq];
        kmA[0] = *(const int4*)&kmp[k0 + 4 * qq];
        kmA[1] = *(const int4*)&kmp[k0 + 16 + 4 * qq];
    }

    for (int ch = 0; ch < 8; ++ch) {
        const int k0 = kw + ch * 32;
        const short8 ka0 = kaA[0], ka1 = kaA[1], ka2 = kaA[2], ka3 = kaA[3];
        const float4 n00 = nfA[0], n01 = nfA[1], n10 = nfA[2], n11 = nfA[3];
        const int4 km0 = kmA[0], km1 = kmA[1];

        if (ch < 7) {
            const int k1 = k0 + 32;
            const unsigned short* kap = KAp + (size_t)(b * 128 + (k1 >> 4)) * 1024;
            #pragma unroll
            for (int gg = 0; gg < 2; ++gg)
                #pragma unroll
                for (int ss = 0; ss < 2; ++ss)
                    kaA[gg * 2 + ss] = *(const short8*)(kap + gg * 1024 + ss * 512 + lane * 8);
            nfA[0] = *(const float4*)&np0[k1 + 4 * qq];
            nfA[1] = *(const float4*)&np0[k1 + 16 + 4 * qq];
            nfA[2] = *(const float4*)&np1[k1 + 4 * qq];
            nfA[3] = *(const float4*)&np1[k1 + 16 + 4 * qq];
            kmA[0] = *(const int4*)&kmp[k1 + 4 * qq];
            kmA[1] = *(const int4*)&kmp[k1 + 16 + 4 * qq];
        }

        // ---- S^T = K·Q^T (per grp, per stream) ----
        const f32x4 zz = (f32x4){0.f, 0.f, 0.f, 0.f};
        f32x4 sI0 = __builtin_amdgcn_mfma_f32_16x16x32_bf16(ka0, qb0, zz, 0, 0, 0);
        f32x4 sI1 = __builtin_amdgcn_mfma_f32_16x16x32_bf16(ka2, qb0, zz, 0, 0, 0);
        f32x4 sC0 = __builtin_amdgcn_mfma_f32_16x16x32_bf16(ka1, qb1, zz, 0, 0, 0);
        f32x4 sC1 = __builtin_amdgcn_mfma_f32_16x16x32_bf16(ka3, qb1, zz, 0, 0, 0);

        // ---- noise mix + masks (reg r of grp g <-> key 16g + 4*qq + r) ----
        float u[8], v[8], mk[8];
        u[0] = fmaf(a0, n00.x, sI0[0]); u[1] = fmaf(a0, n00.y, sI0[1]);
        u[2] = fmaf(a0, n00.z, sI0[2]); u[3] = fmaf(a0, n00.w, sI0[3]);
        u[4] = fmaf(a0, n01.x, sI1[0]); u[5] = fmaf(a0, n01.y, sI1[1]);
        u[6] = fmaf(a0, n01.z, sI1[2]); u[7] = fmaf(a0, n01.w, sI1[3]);
        v[0] = fmaf(a1, n10.x, sC0[0]); v[1] = fmaf(a1, n10.y, sC0[1]);
        v[2] = fmaf(a1, n10.z, sC0[2]); v[3] = fmaf(a1, n10.w, sC0[3]);
        v[4] = fmaf(a1, n11.x, sC1[0]); v[5] = fmaf(a1, n11.y, sC1[1]);
        v[6] = fmaf(a1, n11.z, sC1[2]); v[7] = fmaf(a1, n11.w, sC1[3]);
        mk[0] = (float)km0.x; mk[1] = (float)km0.y; mk[2] = (float)km0.z; mk[3] = (float)km0.w;
        mk[4] = (float)km1.x; mk[5] = (float)km1.y; mk[6] = (float)km1.z; mk[7] = (float)km1.w;

        const unsigned short* vap = VAp + (size_t)(b * 64 + (k0 >> 5)) * 8192;
        short8 va0 = *(const short8*)(vap + 0 * 1024 + 0 * 512 + lane * 8);
        short8 va1 = *(const short8*)(vap + 0 * 1024 + 1 * 512 + lane * 8);

        #pragma unroll
        for (int h = 0; h < H_; ++h) {
            short8 nva0 = va0, nva1 = va1;
            if (h < 7) {
                nva0 = *(const short8*)(vap + (h + 1) * 1024 + lane * 8);
                nva1 = *(const short8*)(vap + (h + 1) * 1024 + 512 + lane * 8);
            }
            float p[8];
            #pragma unroll
            for (int r = 0; r < 8; ++r)
                p[r] = exp2f(fmaf(u[r], w0s[h], fmaf(v[r], w1s[h], bh8[h]))) * mk[r];
            lacc[h] += ((p[0] + p[1]) + (p[2] + p[3])) + ((p[4] + p[5]) + (p[6] + p[7]));

            // pack + cross-lane to P^T B-frag (keys 8*qq..8*qq+7 per lane)
            unsigned pk0 = cvtpk(p[0], p[1]), pk1 = cvtpk(p[2], p[3]);
            unsigned pk2 = cvtpk(p[4], p[5]), pk3 = cvtpk(p[6], p[7]);
            int2v sw0 = __builtin_amdgcn_permlane32_swap((int)pk0, (int)pk2, false, false);
            int2v sw1 = __builtin_amdgcn_permlane32_swap((int)pk1, (int)pk3, false, false);
            int x0 = sw0[0], y0 = sw0[1], x1 = sw1[0], y1 = sw1[1];
            int x0s = __builtin_amdgcn_ds_swizzle(x0, 0x401F);   // xor lane^16
            int y0s = __builtin_amdgcn_ds_swizzle(y0, 0x401F);
            int x1s = __builtin_amdgcn_ds_swizzle(x1, 0x401F);
            int y1s = __builtin_amdgcn_ds_swizzle(y1, 0x401F);
            const bool sel = (qq & 1) != 0;
            uint4 bfu;
            bfu.x = (unsigned)(sel ? y0s : x0);
            bfu.y = (unsigned)(sel ? y1s : x1);
            bfu.z = (unsigned)(sel ? y0  : x0s);
            bfu.w = (unsigned)(sel ? y1  : x1s);
            short8 bf = *(short8*)&bfu;
            acc[h][0] = __builtin_amdgcn_mfma_f32_16x16x32_bf16(va0, bf, acc[h][0], 0, 0, 0);
            acc[h][1] = __builtin_amdgcn_mfma_f32_16x16x32_bf16(va1, bf, acc[h][1], 0, 0, 0);
            va0 = nva0; va1 = nva1;
        }
    }

    // ---- denominators: fold across qq (lanes q, q+16, q+32, q+48) ----
    #pragma unroll
    for (int h = 0; h < H_; ++h) {
        float t = lacc[h] + __shfl_xor(lacc[h], 16, 64);
        lacc[h] = t + __shfl_xor(t, 32, 64);
    }
    if (lane < 16) {
        #pragma unroll
        for (int h = 0; h < H_; ++h) Ls[w][lane][h] = lacc[h];
    }
    __syncthreads();
    if (tid < 128) {
        const int q = tid >> 3, h = tid & 7;
        float l = 0.f;
        #pragma unroll
        for (int ww = 0; ww < 8; ++ww) l += Ls[ww][q][h];
        const float qm = (float)query_mask[b * LQ_ + q0 + q];
        Linv[q][h] = (l > 0.f) ? (qm / l) : 0.f;
    }

    // ---- numerators: per-head cross-wave reduce + direct out ----
    const int qo = tid >> 5, dO = tid & 31;
    #pragma unroll
    for (int h = 0; h < H_; ++h) {
        #pragma unroll
        for (int dh = 0; dh < 2; ++dh)
            #pragma unroll
            for (int r = 0; r < 4; ++r)
                Nb[w][dh * 16 + 4 * qq + r][q16] = acc[h][dh][r];
        __syncthreads();
        float vsum = 0.f;
        #pragma unroll
        for (int ww = 0; ww < 8; ++ww) vsum += Nb[ww][dO][qo];
        const size_t o = ((size_t)b * LQ_ + q0 + qo) * 256 + h * 32 + dO;
        out[o] = fmaf(vsum, Linv[qo][h], resid[o]);
        __syncthreads();
    }
}

// ---------------------------------------------------------------------------
extern "C" void kernel_launch(void* const* d_in, const int* in_sizes, int n_in,
                              void* d_out, int out_size, void* d_ws, size_t ws_size,
                              hipStream_t stream)
{
    (void)in_sizes; (void)n_in; (void)out_size; (void)ws_size;
    const float* queries_it  = (const float*)d_in[0];
    const float* queries_ctx = (const float*)d_in[1];
    const float* keys_it     = (const float*)d_in[2];
    const float* keys_ctx    = (const float*)d_in[3];
    const float* sigma       = (const float*)d_in[4];
    const float* noise       = (const float*)d_in[5];
    const float* Wq_it       = (const float*)d_in[6];
    const float* Wk_it       = (const float*)d_in[7];
    const float* Wq_ctx      = (const float*)d_in[8];
    const float* Wk_ctx      = (const float*)d_in[9];
    const float* Wv          = (const float*)d_in[10];
    const float* W_hdp       = (const float*)d_in[11];
    const float* b_hdp       = (const float*)d_in[12];
    const int*   key_mask    = (const int*)d_in[13];
    const int*   query_mask  = (const int*)d_in[14];
    float* out = (float*)d_out;
    float* ws  = (float*)d_ws;    // needs 3 MB

    proj_qk_kernel<<<dim3(512), dim3(256), 0, stream>>>(
        queries_it, queries_ctx, keys_it, keys_ctx,
        Wq_it, Wq_ctx, Wk_it, Wk_ctx, ws);

    proj_v_kernel<<<dim3(256), dim3(256), 0, stream>>>(keys_it, Wv, ws);

    attn_kernel<<<dim3(LQ_ / 16, B_), dim3(512), 0, stream>>>(
        ws, queries_it, sigma, noise, W_hdp, b_hdp, key_mask, query_mask, out);
}